// Round 5
// baseline (660.590 us; speedup 1.0000x reference)
//
#include <hip/hip_runtime.h>
#include <hip/hip_bf16.h>
#include <stdint.h>
#include <stddef.h>

using bf16  = __hip_bfloat16;
using v4s   = __attribute__((ext_vector_type(4))) short;
using v8s   = __attribute__((ext_vector_type(8))) short;
using f32x4 = __attribute__((ext_vector_type(4))) float;

#define MFMA_16x16x32(a, b, c) __builtin_amdgcn_mfma_f32_16x16x32_bf16((a), (b), (c), 0, 0, 0)

// Async global->LDS DMA, 16B/lane. lds base must be wave-uniform; lane i's
// 16B lands at lds + i*16 (m97-verified pattern).
__device__ __forceinline__ void async_lds16(const bf16* g, bf16* l) {
  __builtin_amdgcn_global_load_lds(
      (const __attribute__((address_space(1))) void*)g,
      (__attribute__((address_space(3))) void*)l, 16, 0, 0);
}

// TBAA-safe bf16 bit pattern as short (memcpy folds to a bit-cast).
__device__ __forceinline__ short bf16_bits(float f) {
  bf16 h = __float2bfloat16(f);
  short s;
  __builtin_memcpy(&s, &h, sizeof(s));
  return s;
}

// ---------------------------------------------------------------------------
// fp32 -> bf16 conversion (RNE), 4 elements/thread via float4.
// ---------------------------------------------------------------------------
__global__ void cvt_f32_bf16(const float* __restrict__ in, bf16* __restrict__ out,
                             int n4) {
  const int i = blockIdx.x * blockDim.x + threadIdx.x;
  if (i >= n4) return;
  const float4 f = ((const float4*)in)[i];
  v4s o;
  o[0] = bf16_bits(f.x);
  o[1] = bf16_bits(f.y);
  o[2] = bf16_bits(f.z);
  o[3] = bf16_bits(f.w);
  *(v4s*)(out + (size_t)i * 4) = o;
}

// ---------------------------------------------------------------------------
// GEMM v10: C[M,N] = A[M,K] @ B[N,K]^T, bf16 in, fp32 accum, bf16/fp32 out.
// 256x256 tile, BK=64, 8 waves (2M x 4N, 128x64 per wave).
//
// v9 post-mortem: phase-pinned prereads put 20/24 ds_reads right before a
// barrier followed by lgkmcnt(0) -> zero overlap window; LDS (2304cyc) and
// MFMA (2483cyc) serialized (measured 5280 cyc/K-tile). v10 un-pins:
// plain C++ LDS reads + MFMA in ONE compute phase per K-tile — hipcc emits
// fine-grained counted lgkmcnt between ds_read and MFMA (m97-verified),
// letting read bursts drain under MFMA execution. The m97 structure's real
// flaw (vmcnt(0) drain at every barrier) stays solved via counted-vmcnt
// double-buffered staging:
//   per iter: compute(k from Lc, unpinned)
//             lgkmcnt(0); barrier#1          [WAR: all waves done reading Lc]
//             stage k+2 -> Lc (8 loads)
//             vmcnt(8)                       [retires k+1, issued ~2500cyc ago]
//             barrier#2                      [RAW: k+1 visible to all waves]
//   tails: k+2>=NKT -> no stage, vmcnt(0); k+1>=NKT -> no wait.
// LDS frag-ordered (conflict-free b128, measured 0 conflicts). 2 barriers/iter.
// ---------------------------------------------------------------------------
template <bool F32OUT>
__global__ __launch_bounds__(512, 2) void gemm_bt10(const bf16* __restrict__ A,
                                                    const bf16* __restrict__ B,
                                                    void* __restrict__ C,
                                                    int M, int N, int K) {
  __shared__ bf16 lds[2][64][512];  // [buf][subtile: A=0..31, B=32..63][frag]
  const int tid  = threadIdx.x;
  const int w    = tid >> 6;
  const int lane = tid & 63;
  const int quad = lane >> 4;
  const int m16  = lane & 15;
  const int wr = w >> 2, wc = w & 3;  // 2 x 4 wave grid
  const int tm = blockIdx.y, tn = blockIdx.x;
  const int NKT = K >> 6;

  const bf16* Ast0 = A + (size_t)(tm * 256 + w * 16 + m16) * K + quad * 8;
  const bf16* Ast1 = Ast0 + (size_t)128 * K;
  const bf16* Bst0 = B + (size_t)(tn * 256 + w * 16 + m16) * K + quad * 8;
  const bf16* Bst1 = Bst0 + (size_t)128 * K;

  auto stage = [&](const bf16* g, bf16* l) {
    async_lds16(g, l);             // kg = 0
    async_lds16(g + 32, l + 512);  // kg = 1
  };
  auto stage_tile = [&](int kt, bf16* L) {
    stage(Ast0 + (size_t)kt * 64, L + (w * 2) * 512);
    stage(Ast1 + (size_t)kt * 64, L + (16 + w * 2) * 512);
    stage(Bst0 + (size_t)kt * 64, L + (32 + w * 2) * 512);
    stage(Bst1 + (size_t)kt * 64, L + (48 + w * 2) * 512);
  };

  f32x4 acc[8][4] = {};

  // ---- prologue: tile0 -> buf0, tile1 -> buf1 (8 loads each) ----
  stage_tile(0, &lds[0][0][0]);
  if (NKT > 1) stage_tile(1, &lds[1][0][0]);
  asm volatile("s_waitcnt vmcnt(8)" ::: "memory");  // tile 0 landed
  __builtin_amdgcn_s_barrier();

  for (int k = 0; k < NKT; ++k) {
    bf16* Lc = &lds[k & 1][0][0];
    // ---- compute tile k: plain reads + MFMA, compiler-scheduled ----
    v8s bfr[4][2];
#pragma unroll
    for (int ni = 0; ni < 4; ++ni)
#pragma unroll
      for (int kg = 0; kg < 2; ++kg)
        bfr[ni][kg] = *(const v8s*)(Lc + (32 + (wc * 4 + ni) * 2 + kg) * 512 + lane * 8);
#pragma unroll
    for (int mi = 0; mi < 8; ++mi) {
      v8s a0 = *(const v8s*)(Lc + ((wr * 8 + mi) * 2 + 0) * 512 + lane * 8);
      v8s a1 = *(const v8s*)(Lc + ((wr * 8 + mi) * 2 + 1) * 512 + lane * 8);
#pragma unroll
      for (int ni = 0; ni < 4; ++ni) {
        acc[mi][ni] = MFMA_16x16x32(a0, bfr[ni][0], acc[mi][ni]);
        acc[mi][ni] = MFMA_16x16x32(a1, bfr[ni][1], acc[mi][ni]);
      }
    }
    // ---- WAR: my Lc reads retired; then all waves' ----
    asm volatile("s_waitcnt lgkmcnt(0)" ::: "memory");
    __builtin_amdgcn_s_barrier();
    // ---- stage tile k+2 into the buffer just freed ----
    if (k + 2 < NKT) stage_tile(k + 2, Lc);
    // ---- RAW: tile k+1 landed (issued a full K-tile ago -> wait ~free) ----
    if (k + 2 < NKT) {
      asm volatile("s_waitcnt vmcnt(8)" ::: "memory");
    } else if (k + 1 < NKT) {
      asm volatile("s_waitcnt vmcnt(0)" ::: "memory");
    }
    __builtin_amdgcn_s_barrier();
  }

  // ---- epilogue ----
#pragma unroll
  for (int mi = 0; mi < 8; ++mi)
#pragma unroll
    for (int ni = 0; ni < 4; ++ni) {
      const int row = tm * 256 + wr * 128 + mi * 16 + quad * 4;
      const int col = tn * 256 + wc * 64 + ni * 16 + m16;
#pragma unroll
      for (int r = 0; r < 4; ++r) {
        if (F32OUT)
          ((float*)C)[(size_t)(row + r) * N + col] = acc[mi][ni][r];
        else
          ((bf16*)C)[(size_t)(row + r) * N + col] = __float2bfloat16(acc[mi][ni][r]);
      }
    }
}

// ---------------------------------------------------------------------------
// RoPE cos/sin table: tab[t][f] = (cos(t*invf), sin(t*invf)), f in [0,64).
// NOTE: launched AFTER the QKV GEMM — the table lives in the wk/wv staging
// region, which is only dead once the QKV GEMM has consumed it.
// ---------------------------------------------------------------------------
__global__ void rope_tab(float2* __restrict__ tab) {
  const int t = blockIdx.x;
  const int f = threadIdx.x;  // 0..63
  const float invf = powf(10000.0f, -(float)f * (1.0f / 64.0f));
  const float ang  = (float)t * invf;
  tab[t * 64 + f] = make_float2(cosf(ang), sinf(ang));
}

// ---------------------------------------------------------------------------
// RoPE, IN PLACE on qkv[t][6144]: q cols [h*128), k cols 4096+[hk*128).
// Scale 1/sqrt(128) folded into q. grid = (T, 40), block = 128 (=D).
// ---------------------------------------------------------------------------
__global__ void rope_kernel(bf16* __restrict__ qkv, const float2* __restrict__ tab) {
  const int t  = blockIdx.x;
  const int hh = blockIdx.y;
  const int d  = threadIdx.x;  // 0..127
  const float2 cs = tab[t * 64 + (d & 63)];
  const float c = cs.x;
  const float s = cs.y;
  const bool isq = (hh < 32);
  bf16* ptr = qkv + (size_t)t * 6144 + (isq ? hh * 128 : 4096 + (hh - 32) * 128);
  const float x   = __bfloat162float(ptr[d]);
  const float xp  = __bfloat162float(ptr[d ^ 64]);
  __syncthreads();
  const float rot = (d < 64) ? -xp : xp;
  const float outv = (x * c + rot * s) * (isq ? 0.08838834764831845f : 1.0f);
  ptr[d] = __float2bfloat16(outv);
}

// ---------------------------------------------------------------------------
// V transpose: qkv[t][5120 + c] -> vT[c][t]  (c in [0,1024), stride-2048 out).
// ---------------------------------------------------------------------------
__global__ void vtrans_kernel(const bf16* __restrict__ qkv, bf16* __restrict__ vt) {
  __shared__ bf16 tile[32][34];
  const int t0 = blockIdx.x * 32, c0 = blockIdx.y * 32;
  const int tx = threadIdx.x, ty = threadIdx.y;  // 32, 8
#pragma unroll
  for (int i = 0; i < 4; ++i)
    tile[ty + 8 * i][tx] = qkv[(size_t)(t0 + ty + 8 * i) * 6144 + 5120 + c0 + tx];
  __syncthreads();
#pragma unroll
  for (int i = 0; i < 4; ++i)
    vt[(size_t)(c0 + ty + 8 * i) * 2048 + t0 + tx] = tile[tx][ty + 8 * i];
}

// ---------------------------------------------------------------------------
// Fused causal flash attention v4 — pipelined, load-balanced.
// (unchanged — verified in round 2)
// ---------------------------------------------------------------------------
__global__ __launch_bounds__(256) void attn_fused4(const bf16* __restrict__ QKV,
                                                   const bf16* __restrict__ Vt,
                                                   bf16* __restrict__ O) {
  const int bx = (int)blockIdx.x;
  const int h  = (int)blockIdx.y;
  const int qt = (h < 16) ? (15 - bx) : bx;  // complementary pairing across CU pair
  const int hk = h >> 2;
  const int tid = threadIdx.x, w = tid >> 6, lane = tid & 63;
  const int quad = lane >> 4, m16 = lane & 15;
  __shared__ bf16 Ks[32 * 512];                             // 32 KB K frags
  __shared__ bf16 Vs[32 * 512];                             // 32 KB Vt frags
  __shared__ __attribute__((aligned(16))) short Ps[4][2048];  // 16 KB P^T (4 KB/wave)
  short* Pw = Ps[w];

  // Q^T B-frags (scale folded in by rope); wave owns q cols w*32 + ni*16 + m16
  v8s qf[2][4];
#pragma unroll
  for (int ni = 0; ni < 2; ++ni)
#pragma unroll
    for (int dk = 0; dk < 4; ++dk)
      qf[ni][dk] = *(const v8s*)(QKV + (size_t)(qt * 128 + w * 32 + ni * 16 + m16) * 6144 +
                                 h * 128 + dk * 32 + quad * 8);

  // Per-lane staging source bases (row m16, 16B at col w*32 + quad*8).
  const bf16* kg = QKV + (size_t)m16 * 6144 + 4096 + hk * 128 + w * 32 + quad * 8;
  const bf16* vg = Vt + (size_t)(hk * 128 + m16) * 2048 + w * 32 + quad * 8;

  f32x4 acc[8][2] = {};
  float m_run[2] = {-1e30f, -1e30f}, l_run[2] = {0.f, 0.f};

  // Prologue: stage tile 0 (K first, then V — issue order matters for vmcnt).
#pragma unroll
  for (int mi = 0; mi < 8; ++mi)
    async_lds16(kg + (size_t)mi * 16 * 6144, &Ks[(mi * 4 + w) * 512]);
#pragma unroll
  for (int mi = 0; mi < 8; ++mi)
    async_lds16(vg + (size_t)mi * 16 * 2048, &Vs[(mi * 4 + w) * 512]);

  for (int kt = 0; kt <= qt; ++kt) {
    // ---- top: K(kt) landed (8 V loads legitimately in flight) ----
    asm volatile("s_waitcnt vmcnt(8)" ::: "memory");
    __builtin_amdgcn_s_barrier();
    // ---- S^T = K (A-frags from LDS) * Q^T (B-frags in regs) ----
    f32x4 s[8][2];
    __builtin_amdgcn_s_setprio(1);
#pragma unroll
    for (int mi = 0; mi < 8; ++mi) {
      s[mi][0] = f32x4{0.f, 0.f, 0.f, 0.f};
      s[mi][1] = f32x4{0.f, 0.f, 0.f, 0.f};
#pragma unroll
      for (int dk = 0; dk < 4; ++dk) {
        v8s af = *(const v8s*)&Ks[(mi * 4 + dk) * 512 + lane * 8];
        s[mi][0] = MFMA_16x16x32(af, qf[0][dk], s[mi][0]);
        s[mi][1] = MFMA_16x16x32(af, qf[1][dk], s[mi][1]);
      }
    }
    __builtin_amdgcn_s_setprio(0);
    // ---- drain V(kt); all waves done with Ks -> overwrite with K(kt+1) ----
    asm volatile("s_waitcnt vmcnt(0)" ::: "memory");
    __builtin_amdgcn_s_barrier();
    if (kt < qt) {
      const bf16* kg2 = kg + (size_t)(kt + 1) * 128 * 6144;
#pragma unroll
      for (int mi = 0; mi < 8; ++mi)
        async_lds16(kg2 + (size_t)mi * 16 * 6144, &Ks[(mi * 4 + w) * 512]);
    }
    if (kt == qt) {  // causal mask, diagonal tile only
#pragma unroll
      for (int mi = 0; mi < 8; ++mi)
#pragma unroll
        for (int ni = 0; ni < 2; ++ni)
#pragma unroll
          for (int r = 0; r < 4; ++r)
            if (mi * 16 + quad * 4 + r > w * 32 + ni * 16 + m16) s[mi][ni][r] = -1e30f;
    }
    // ---- online softmax over k (per-lane scalar state per ni) ----
#pragma unroll
    for (int ni = 0; ni < 2; ++ni) {
      float mx = -1e30f;
#pragma unroll
      for (int mi = 0; mi < 8; ++mi)
#pragma unroll
        for (int r = 0; r < 4; ++r) mx = fmaxf(mx, s[mi][ni][r]);
      mx = fmaxf(mx, __shfl_xor(mx, 16));
      mx = fmaxf(mx, __shfl_xor(mx, 32));
      const float mnew = fmaxf(m_run[ni], mx);
      const float alpha = __expf(m_run[ni] - mnew);
      m_run[ni] = mnew;
      float rs = 0.f;
#pragma unroll
      for (int mi = 0; mi < 8; ++mi)
#pragma unroll
        for (int r = 0; r < 4; ++r) {
          const float p = __expf(s[mi][ni][r] - mnew);
          s[mi][ni][r] = p;
          rs += p;
        }
      rs += __shfl_xor(rs, 16);
      rs += __shfl_xor(rs, 32);
      l_run[ni] = l_run[ni] * alpha + rs;
#pragma unroll
      for (int mi2 = 0; mi2 < 8; ++mi2)
#pragma unroll
        for (int r = 0; r < 4; ++r) acc[mi2][ni][r] *= alpha;
    }
    // ---- half A: pack P^T (mi 0-3 -> kp 0,1) and PV over kp 0,1 ----
#pragma unroll
    for (int mi = 0; mi < 4; ++mi)
#pragma unroll
      for (int ni = 0; ni < 2; ++ni) {
        v4s p4;
#pragma unroll
        for (int r = 0; r < 4; ++r) p4[r] = bf16_bits(s[mi][ni][r]);
        const int base = (ni * 2 + (mi >> 1)) * 512 +
                         ((mi & 1) * 2 + (quad >> 1)) * 128 + m16 * 8 + (quad & 1) * 4;
        *(v4s*)&Pw[base] = p4;
      }
    asm volatile("" ::: "memory");  // same-wave: P writes before P frag reads
    __builtin_amdgcn_s_setprio(1);
#pragma unroll
    for (int kpl = 0; kpl < 2; ++kpl) {
      v8s pf0 = *(const v8s*)&Pw[(0 * 2 + kpl) * 512 + lane * 8];
      v8s pf1 = *(const v8s*)&Pw[(1 * 2 + kpl) * 512 + lane * 8];
#pragma unroll
      for (int mi2 = 0; mi2 < 8; ++mi2) {
        v8s vf = *(const v8s*)&Vs[(mi2 * 4 + kpl) * 512 + lane * 8];
        acc[mi2][0] = MFMA_16x16x32(vf, pf0, acc[mi2][0]);
        acc[mi2][1] = MFMA_16x16x32(vf, pf1, acc[mi2][1]);
      }
    }
    __builtin_amdgcn_s_setprio(0);
    asm volatile("" ::: "memory");  // half-A reads before half-B overwrites
    // ---- half B: pack P^T (mi 4-7 -> kp 2,3) and PV over kp 2,3 ----
#pragma unroll
    for (int mi = 4; mi < 8; ++mi)
#pragma unroll
      for (int ni = 0; ni < 2; ++ni) {
        const int mloc = mi - 4;
        v4s p4;
#pragma unroll
        for (int r = 0; r < 4; ++r) p4[r] = bf16_bits(s[mi][ni][r]);
        const int base = (ni * 2 + (mloc >> 1)) * 512 +
                         ((mloc & 1) * 2 + (quad >> 1)) * 128 + m16 * 8 + (quad & 1) * 4;
        *(v4s*)&Pw[base] = p4;
      }
    asm volatile("" ::: "memory");
    __builtin_amdgcn_s_setprio(1);
#pragma unroll
    for (int kpl = 0; kpl < 2; ++kpl) {
      v8s pf0 = *(const v8s*)&Pw[(0 * 2 + kpl) * 512 + lane * 8];
      v8s pf1 = *(const v8s*)&Pw[(1 * 2 + kpl) * 512 + lane * 8];
#pragma unroll
      for (int mi2 = 0; mi2 < 8; ++mi2) {
        v8s vf = *(const v8s*)&Vs[(mi2 * 4 + 2 + kpl) * 512 + lane * 8];
        acc[mi2][0] = MFMA_16x16x32(vf, pf0, acc[mi2][0]);
        acc[mi2][1] = MFMA_16x16x32(vf, pf1, acc[mi2][1]);
      }
    }
    __builtin_amdgcn_s_setprio(0);
    // ---- all waves done with Vs -> overwrite with V(kt+1) ----
    asm volatile("" ::: "memory");
    __builtin_amdgcn_s_barrier();
    if (kt < qt) {
      const bf16* vg2 = vg + (size_t)(kt + 1) * 128;
#pragma unroll
      for (int mi = 0; mi < 8; ++mi)
        async_lds16(vg2 + (size_t)mi * 16 * 2048, &Vs[(mi * 4 + w) * 512]);
    }
  }
  // ---- epilogue: O[q][h*128+d], 4 consecutive d per lane -> 8B stores ----
#pragma unroll
  for (int ni = 0; ni < 2; ++ni) {
    const float rl = 1.0f / l_run[ni];
    const size_t qrow = qt * 128 + w * 32 + ni * 16 + m16;
#pragma unroll
    for (int mi2 = 0; mi2 < 8; ++mi2) {
      v4s o4;
#pragma unroll
      for (int r = 0; r < 4; ++r) o4[r] = bf16_bits(acc[mi2][ni][r] * rl);
      *(v4s*)(O + qrow * 4096 + h * 128 + mi2 * 16 + quad * 4) = o4;
    }
  }
}

// ---------------------------------------------------------------------------
extern "C" void kernel_launch(void* const* d_in, const int* in_sizes, int n_in,
                              void* d_out, int out_size, void* d_ws, size_t ws_size,
                              hipStream_t stream) {
  const float* stm = (const float*)d_in[0];  // [2048][4096] fp32
  const float* w_q = (const float*)d_in[1];  // [4096][4096] fp32
  const float* w_k = (const float*)d_in[2];  // [1024][4096] fp32
  const float* w_v = (const float*)d_in[3];  // [1024][4096] fp32
  const float* w_o = (const float*)d_in[4];  // [4096][4096] fp32
  float* out = (float*)d_out;                // [2048][4096] fp32

  const size_t M_STM = (size_t)2048 * 4096;  //  8M
  const size_t M_WQ  = (size_t)4096 * 4096;  // 16M
  const size_t M_WK  = (size_t)1024 * 4096;  //  4M

  bf16* ws      = (bf16*)d_ws;
  // [0, 24M): wqkv (wq 16M | wk 4M | wv 4M) — LIVE until QKV gemm completes.
  // After QKV gemm: wo overlays [0,16M), vT overlays [16M,18M),
  //                 ropeT overlays [18M,18.5M) (dead wk/wv tail).
  bf16* wqkv_bf = ws;
  bf16* wo_bf   = ws;
  bf16* vT      = ws + M_WQ;
  float2* ropeT = (float2*)(ws + 18 * 1024 * 1024);
  // [24M, 32M): stm_bf; after QKV gemm: o_buf
  bf16* stm_bf  = ws + 24 * 1024 * 1024;
  bf16* o_buf   = stm_bf;
  // [32M, ~44.6M): qkv_buf [2048][6144]
  bf16* qkv_buf = ws + 32 * 1024 * 1024;

  cvt_f32_bf16<<<(int)(M_STM / 1024), 256, 0, stream>>>(stm, stm_bf, (int)(M_STM / 4));
  cvt_f32_bf16<<<(int)(M_WQ / 1024), 256, 0, stream>>>(w_q, wqkv_bf, (int)(M_WQ / 4));
  cvt_f32_bf16<<<(int)(M_WK / 1024), 256, 0, stream>>>(w_k, wqkv_bf + M_WQ, (int)(M_WK / 4));
  cvt_f32_bf16<<<(int)(M_WK / 1024), 256, 0, stream>>>(w_v, wqkv_bf + M_WQ + M_WK, (int)(M_WK / 4));

  // fused QKV projection: [2048,4096] x [6144,4096]^T -> [2048,6144]
  gemm_bt10<false><<<dim3(24, 8), 512, 0, stream>>>(stm_bf, wqkv_bf, qkv_buf, 2048, 6144, 4096);

  // wqkv dead NOW; stage w_o into its region and build the rope table in the
  // dead wk/wv tail (launching rope_tab before the QKV gemm clobbers w_k!).
  cvt_f32_bf16<<<(int)(M_WQ / 1024), 256, 0, stream>>>(w_o, wo_bf, (int)(M_WQ / 4));
  rope_tab<<<2048, 64, 0, stream>>>(ropeT);

  rope_kernel<<<dim3(2048, 40), 128, 0, stream>>>(qkv_buf, ropeT);
  vtrans_kernel<<<dim3(64, 32), dim3(32, 8), 0, stream>>>(qkv_buf, vT);
  attn_fused4<<<dim3(16, 32), 256, 0, stream>>>(qkv_buf, vT, o_buf);

  // output projection: [2048,4096] x [4096,4096]^T -> fp32 out
  gemm_bt10<true><<<dim3(16, 8), 512, 0, stream>>>(o_buf, wo_bf, out, 2048, 4096, 4096);
}

// Round 6
// 605.093 us; speedup vs baseline: 1.0917x; 1.0917x over previous
//
#include <hip/hip_runtime.h>
#include <hip/hip_bf16.h>
#include <stdint.h>
#include <stddef.h>

using bf16  = __hip_bfloat16;
using v4s   = __attribute__((ext_vector_type(4))) short;
using v8s   = __attribute__((ext_vector_type(8))) short;
using f32x4 = __attribute__((ext_vector_type(4))) float;

#define MFMA_16x16x32(a, b, c) __builtin_amdgcn_mfma_f32_16x16x32_bf16((a), (b), (c), 0, 0, 0)

// Async global->LDS DMA, 16B/lane. lds base must be wave-uniform; lane i's
// 16B lands at lds + i*16 (m97-verified pattern).
__device__ __forceinline__ void async_lds16(const bf16* g, bf16* l) {
  __builtin_amdgcn_global_load_lds(
      (const __attribute__((address_space(1))) void*)g,
      (__attribute__((address_space(3))) void*)l, 16, 0, 0);
}

// TBAA-safe bf16 bit pattern as short (memcpy folds to a bit-cast).
__device__ __forceinline__ short bf16_bits(float f) {
  bf16 h = __float2bfloat16(f);
  short s;
  __builtin_memcpy(&s, &h, sizeof(s));
  return s;
}

// ---------------------------------------------------------------------------
// fp32 -> bf16 conversion (RNE), 4 elements/thread via float4.
// ---------------------------------------------------------------------------
__global__ void cvt_f32_bf16(const float* __restrict__ in, bf16* __restrict__ out,
                             int n4) {
  const int i = blockIdx.x * blockDim.x + threadIdx.x;
  if (i >= n4) return;
  const float4 f = ((const float4*)in)[i];
  v4s o;
  o[0] = bf16_bits(f.x);
  o[1] = bf16_bits(f.y);
  o[2] = bf16_bits(f.z);
  o[3] = bf16_bits(f.w);
  *(v4s*)(out + (size_t)i * 4) = o;
}

// ---------------------------------------------------------------------------
// GEMM v11: C[M,N] = A[M,K] @ B[N,K]^T, bf16 in, fp32 accum, bf16/fp32 out.
// 256x256 tile, BK=64, 8 waves (2M x 4N, 128x64 per wave).
//
// = v8's hardware-verified 4-phase skeleton (2 barriers/phase, staging
// A1(k+1)/B0(k+2)/B1(k+2)/A0(k+2) at p1..p4, single vmcnt(6) per K-tile at
// p4, tail vmcnt(0)) with two deltas vs v8:
//  * reads balanced 12/4/8/0 across phases (v8: 16/0/8/0) — shrinks the
//    per-phase LDS burst all waves stall on at lgkmcnt(0); the 2-waves/SIMD
//    alternation + setprio hides the smaller bursts under the other wave's
//    MFMA. (The GEMM is LDS-pipe-bound: 192 b128 reads/CU/K-tile ~2310cyc
//    vs MFMA wall-clock 621cyc across 4 SIMDs.)
//  * no sched_barrier(0) pins (m141: pinning defeats compiler scheduling;
//    ds_reads are compiler-tracked so correctness never relied on them).
// ---------------------------------------------------------------------------
template <bool F32OUT>
__global__ __launch_bounds__(512, 2) void gemm_bt11(const bf16* __restrict__ A,
                                                    const bf16* __restrict__ B,
                                                    void* __restrict__ C,
                                                    int M, int N, int K) {
  __shared__ bf16 lds[2][64][512];  // [buf][subtile: A=0..31, B=32..63][frag]
  const int tid  = threadIdx.x;
  const int w    = tid >> 6;
  const int lane = tid & 63;
  const int quad = lane >> 4;
  const int m16  = lane & 15;
  const int wr = w >> 2, wc = w & 3;  // 2 x 4 wave grid
  const int tm = blockIdx.y, tn = blockIdx.x;
  const int NKT = K >> 6;

  const bf16* Ast0 = A + (size_t)(tm * 256 + w * 16 + m16) * K + quad * 8;
  const bf16* Ast1 = Ast0 + (size_t)128 * K;
  const bf16* Bst0 = B + (size_t)(tn * 256 + w * 16 + m16) * K + quad * 8;
  const bf16* Bst1 = Bst0 + (size_t)128 * K;

  auto stage = [&](const bf16* g, bf16* l) {
    async_lds16(g, l);             // kg = 0
    async_lds16(g + 32, l + 512);  // kg = 1
  };

  f32x4 acc[8][4] = {};

  // ---- prologue: tile0 full, tile1 all but A1 (7 stages, order matters) ----
  {
    bf16* L0 = &lds[0][0][0];
    bf16* L1 = &lds[1][0][0];
    stage(Bst0, L0 + (32 + w * 2) * 512);
    stage(Bst1, L0 + (48 + w * 2) * 512);
    stage(Ast0, L0 + (w * 2) * 512);
    stage(Ast1, L0 + (16 + w * 2) * 512);
    stage(Bst0 + 64, L1 + (32 + w * 2) * 512);
    stage(Bst1 + 64, L1 + (48 + w * 2) * 512);
    stage(Ast0 + 64, L1 + (w * 2) * 512);
  }
  // ledger: 14 loads out; retire tile0's 8 -> {B0(1),B1(1),A0(1)} = 6 left.
  asm volatile("s_waitcnt vmcnt(6)" ::: "memory");
  __builtin_amdgcn_s_barrier();

  for (int k = 0; k < NKT; ++k) {
    bf16* Lc = &lds[k & 1][0][0];
    bf16* Ln = &lds[(k & 1) ^ 1][0][0];
    v8s af[4][2], bf01[2][2], bf23[2][2];
    // =========== p1: reads af03+bf01 (12); MFMA af03 x bf01 ===========
#pragma unroll
    for (int mi = 0; mi < 4; ++mi)
#pragma unroll
      for (int kg = 0; kg < 2; ++kg)
        af[mi][kg] = *(const v8s*)(Lc + ((wr * 8 + mi) * 2 + kg) * 512 + lane * 8);
#pragma unroll
    for (int ni = 0; ni < 2; ++ni)
#pragma unroll
      for (int kg = 0; kg < 2; ++kg)
        bf01[ni][kg] = *(const v8s*)(Lc + (32 + (wc * 4 + ni) * 2 + kg) * 512 + lane * 8);
    if (k + 1 < NKT) stage(Ast1 + (size_t)(k + 1) * 64, Ln + (16 + w * 2) * 512);
    __builtin_amdgcn_s_barrier();
    asm volatile("s_waitcnt lgkmcnt(0)" ::: "memory");
    __builtin_amdgcn_s_setprio(1);
#pragma unroll
    for (int mi = 0; mi < 4; ++mi)
#pragma unroll
      for (int ni = 0; ni < 2; ++ni) {
        acc[mi][ni] = MFMA_16x16x32(af[mi][0], bf01[ni][0], acc[mi][ni]);
        acc[mi][ni] = MFMA_16x16x32(af[mi][1], bf01[ni][1], acc[mi][ni]);
      }
    __builtin_amdgcn_s_setprio(0);
    __builtin_amdgcn_s_barrier();
    // =========== p2: reads bf23 (4); MFMA af03 x bf23 ===========
#pragma unroll
    for (int ni = 0; ni < 2; ++ni)
#pragma unroll
      for (int kg = 0; kg < 2; ++kg)
        bf23[ni][kg] = *(const v8s*)(Lc + (32 + (wc * 4 + 2 + ni) * 2 + kg) * 512 + lane * 8);
    if (k + 2 < NKT) stage(Bst0 + (size_t)(k + 2) * 64, Lc + (32 + w * 2) * 512);
    __builtin_amdgcn_s_barrier();
    asm volatile("s_waitcnt lgkmcnt(0)" ::: "memory");
    __builtin_amdgcn_s_setprio(1);
#pragma unroll
    for (int mi = 0; mi < 4; ++mi)
#pragma unroll
      for (int ni = 0; ni < 2; ++ni) {
        acc[mi][2 + ni] = MFMA_16x16x32(af[mi][0], bf23[ni][0], acc[mi][2 + ni]);
        acc[mi][2 + ni] = MFMA_16x16x32(af[mi][1], bf23[ni][1], acc[mi][2 + ni]);
      }
    __builtin_amdgcn_s_setprio(0);
    __builtin_amdgcn_s_barrier();
    // =========== p3: reads af47 (8); MFMA af47 x bf23 ===========
#pragma unroll
    for (int mi = 0; mi < 4; ++mi)
#pragma unroll
      for (int kg = 0; kg < 2; ++kg)
        af[mi][kg] = *(const v8s*)(Lc + ((wr * 8 + 4 + mi) * 2 + kg) * 512 + lane * 8);
    if (k + 2 < NKT) stage(Bst1 + (size_t)(k + 2) * 64, Lc + (48 + w * 2) * 512);
    __builtin_amdgcn_s_barrier();
    asm volatile("s_waitcnt lgkmcnt(0)" ::: "memory");
    __builtin_amdgcn_s_setprio(1);
#pragma unroll
    for (int mi = 0; mi < 4; ++mi)
#pragma unroll
      for (int ni = 0; ni < 2; ++ni) {
        acc[4 + mi][2 + ni] = MFMA_16x16x32(af[mi][0], bf23[ni][0], acc[4 + mi][2 + ni]);
        acc[4 + mi][2 + ni] = MFMA_16x16x32(af[mi][1], bf23[ni][1], acc[4 + mi][2 + ni]);
      }
    __builtin_amdgcn_s_setprio(0);
    __builtin_amdgcn_s_barrier();
    // =========== p4: no reads; MFMA af47 x bf01 ===========
    if (k + 2 < NKT) stage(Ast0 + (size_t)(k + 2) * 64, Lc + (w * 2) * 512);
    if (k < NKT - 2) {
      asm volatile("s_waitcnt vmcnt(6)" ::: "memory");
    } else {
      asm volatile("s_waitcnt vmcnt(0)" ::: "memory");
    }
    __builtin_amdgcn_s_barrier();
    __builtin_amdgcn_s_setprio(1);
#pragma unroll
    for (int mi = 0; mi < 4; ++mi)
#pragma unroll
      for (int ni = 0; ni < 2; ++ni) {
        acc[4 + mi][ni] = MFMA_16x16x32(af[mi][0], bf01[ni][0], acc[4 + mi][ni]);
        acc[4 + mi][ni] = MFMA_16x16x32(af[mi][1], bf01[ni][1], acc[4 + mi][ni]);
      }
    __builtin_amdgcn_s_setprio(0);
    __builtin_amdgcn_s_barrier();
  }

  // ---- epilogue ----
#pragma unroll
  for (int mi = 0; mi < 8; ++mi)
#pragma unroll
    for (int ni = 0; ni < 4; ++ni) {
      const int row = tm * 256 + wr * 128 + mi * 16 + quad * 4;
      const int col = tn * 256 + wc * 64 + ni * 16 + m16;
#pragma unroll
      for (int r = 0; r < 4; ++r) {
        if (F32OUT)
          ((float*)C)[(size_t)(row + r) * N + col] = acc[mi][ni][r];
        else
          ((bf16*)C)[(size_t)(row + r) * N + col] = __float2bfloat16(acc[mi][ni][r]);
      }
    }
}

// ---------------------------------------------------------------------------
// RoPE cos/sin table: tab[t][f] = (cos(t*invf), sin(t*invf)), f in [0,64).
// NOTE: launched AFTER the QKV GEMM — the table lives in the wk/wv staging
// region, which is only dead once the QKV GEMM has consumed it.
// ---------------------------------------------------------------------------
__global__ void rope_tab(float2* __restrict__ tab) {
  const int t = blockIdx.x;
  const int f = threadIdx.x;  // 0..63
  const float invf = powf(10000.0f, -(float)f * (1.0f / 64.0f));
  const float ang  = (float)t * invf;
  tab[t * 64 + f] = make_float2(cosf(ang), sinf(ang));
}

// ---------------------------------------------------------------------------
// RoPE, IN PLACE on qkv[t][6144]: q cols [h*128), k cols 4096+[hk*128).
// Scale 1/sqrt(128) folded into q. grid = (T, 40), block = 128 (=D).
// ---------------------------------------------------------------------------
__global__ void rope_kernel(bf16* __restrict__ qkv, const float2* __restrict__ tab) {
  const int t  = blockIdx.x;
  const int hh = blockIdx.y;
  const int d  = threadIdx.x;  // 0..127
  const float2 cs = tab[t * 64 + (d & 63)];
  const float c = cs.x;
  const float s = cs.y;
  const bool isq = (hh < 32);
  bf16* ptr = qkv + (size_t)t * 6144 + (isq ? hh * 128 : 4096 + (hh - 32) * 128);
  const float x   = __bfloat162float(ptr[d]);
  const float xp  = __bfloat162float(ptr[d ^ 64]);
  __syncthreads();
  const float rot = (d < 64) ? -xp : xp;
  const float outv = (x * c + rot * s) * (isq ? 0.08838834764831845f : 1.0f);
  ptr[d] = __float2bfloat16(outv);
}

// ---------------------------------------------------------------------------
// V transpose: qkv[t][5120 + c] -> vT[c][t]  (c in [0,1024), stride-2048 out).
// ---------------------------------------------------------------------------
__global__ void vtrans_kernel(const bf16* __restrict__ qkv, bf16* __restrict__ vt) {
  __shared__ bf16 tile[32][34];
  const int t0 = blockIdx.x * 32, c0 = blockIdx.y * 32;
  const int tx = threadIdx.x, ty = threadIdx.y;  // 32, 8
#pragma unroll
  for (int i = 0; i < 4; ++i)
    tile[ty + 8 * i][tx] = qkv[(size_t)(t0 + ty + 8 * i) * 6144 + 5120 + c0 + tx];
  __syncthreads();
#pragma unroll
  for (int i = 0; i < 4; ++i)
    vt[(size_t)(c0 + ty + 8 * i) * 2048 + t0 + tx] = tile[tx][ty + 8 * i];
}

// ---------------------------------------------------------------------------
// Fused causal flash attention v4 — pipelined, load-balanced.
// (unchanged — verified in rounds 2/4)
// ---------------------------------------------------------------------------
__global__ __launch_bounds__(256) void attn_fused4(const bf16* __restrict__ QKV,
                                                   const bf16* __restrict__ Vt,
                                                   bf16* __restrict__ O) {
  const int bx = (int)blockIdx.x;
  const int h  = (int)blockIdx.y;
  const int qt = (h < 16) ? (15 - bx) : bx;  // complementary pairing across CU pair
  const int hk = h >> 2;
  const int tid = threadIdx.x, w = tid >> 6, lane = tid & 63;
  const int quad = lane >> 4, m16 = lane & 15;
  __shared__ bf16 Ks[32 * 512];                             // 32 KB K frags
  __shared__ bf16 Vs[32 * 512];                             // 32 KB Vt frags
  __shared__ __attribute__((aligned(16))) short Ps[4][2048];  // 16 KB P^T (4 KB/wave)
  short* Pw = Ps[w];

  // Q^T B-frags (scale folded in by rope); wave owns q cols w*32 + ni*16 + m16
  v8s qf[2][4];
#pragma unroll
  for (int ni = 0; ni < 2; ++ni)
#pragma unroll
    for (int dk = 0; dk < 4; ++dk)
      qf[ni][dk] = *(const v8s*)(QKV + (size_t)(qt * 128 + w * 32 + ni * 16 + m16) * 6144 +
                                 h * 128 + dk * 32 + quad * 8);

  // Per-lane staging source bases (row m16, 16B at col w*32 + quad*8).
  const bf16* kg = QKV + (size_t)m16 * 6144 + 4096 + hk * 128 + w * 32 + quad * 8;
  const bf16* vg = Vt + (size_t)(hk * 128 + m16) * 2048 + w * 32 + quad * 8;

  f32x4 acc[8][2] = {};
  float m_run[2] = {-1e30f, -1e30f}, l_run[2] = {0.f, 0.f};

  // Prologue: stage tile 0 (K first, then V — issue order matters for vmcnt).
#pragma unroll
  for (int mi = 0; mi < 8; ++mi)
    async_lds16(kg + (size_t)mi * 16 * 6144, &Ks[(mi * 4 + w) * 512]);
#pragma unroll
  for (int mi = 0; mi < 8; ++mi)
    async_lds16(vg + (size_t)mi * 16 * 2048, &Vs[(mi * 4 + w) * 512]);

  for (int kt = 0; kt <= qt; ++kt) {
    // ---- top: K(kt) landed (8 V loads legitimately in flight) ----
    asm volatile("s_waitcnt vmcnt(8)" ::: "memory");
    __builtin_amdgcn_s_barrier();
    // ---- S^T = K (A-frags from LDS) * Q^T (B-frags in regs) ----
    f32x4 s[8][2];
    __builtin_amdgcn_s_setprio(1);
#pragma unroll
    for (int mi = 0; mi < 8; ++mi) {
      s[mi][0] = f32x4{0.f, 0.f, 0.f, 0.f};
      s[mi][1] = f32x4{0.f, 0.f, 0.f, 0.f};
#pragma unroll
      for (int dk = 0; dk < 4; ++dk) {
        v8s af = *(const v8s*)&Ks[(mi * 4 + dk) * 512 + lane * 8];
        s[mi][0] = MFMA_16x16x32(af, qf[0][dk], s[mi][0]);
        s[mi][1] = MFMA_16x16x32(af, qf[1][dk], s[mi][1]);
      }
    }
    __builtin_amdgcn_s_setprio(0);
    // ---- drain V(kt); all waves done with Ks -> overwrite with K(kt+1) ----
    asm volatile("s_waitcnt vmcnt(0)" ::: "memory");
    __builtin_amdgcn_s_barrier();
    if (kt < qt) {
      const bf16* kg2 = kg + (size_t)(kt + 1) * 128 * 6144;
#pragma unroll
      for (int mi = 0; mi < 8; ++mi)
        async_lds16(kg2 + (size_t)mi * 16 * 6144, &Ks[(mi * 4 + w) * 512]);
    }
    if (kt == qt) {  // causal mask, diagonal tile only
#pragma unroll
      for (int mi = 0; mi < 8; ++mi)
#pragma unroll
        for (int ni = 0; ni < 2; ++ni)
#pragma unroll
          for (int r = 0; r < 4; ++r)
            if (mi * 16 + quad * 4 + r > w * 32 + ni * 16 + m16) s[mi][ni][r] = -1e30f;
    }
    // ---- online softmax over k (per-lane scalar state per ni) ----
#pragma unroll
    for (int ni = 0; ni < 2; ++ni) {
      float mx = -1e30f;
#pragma unroll
      for (int mi = 0; mi < 8; ++mi)
#pragma unroll
        for (int r = 0; r < 4; ++r) mx = fmaxf(mx, s[mi][ni][r]);
      mx = fmaxf(mx, __shfl_xor(mx, 16));
      mx = fmaxf(mx, __shfl_xor(mx, 32));
      const float mnew = fmaxf(m_run[ni], mx);
      const float alpha = __expf(m_run[ni] - mnew);
      m_run[ni] = mnew;
      float rs = 0.f;
#pragma unroll
      for (int mi = 0; mi < 8; ++mi)
#pragma unroll
        for (int r = 0; r < 4; ++r) {
          const float p = __expf(s[mi][ni][r] - mnew);
          s[mi][ni][r] = p;
          rs += p;
        }
      rs += __shfl_xor(rs, 16);
      rs += __shfl_xor(rs, 32);
      l_run[ni] = l_run[ni] * alpha + rs;
#pragma unroll
      for (int mi2 = 0; mi2 < 8; ++mi2)
#pragma unroll
        for (int r = 0; r < 4; ++r) acc[mi2][ni][r] *= alpha;
    }
    // ---- half A: pack P^T (mi 0-3 -> kp 0,1) and PV over kp 0,1 ----
#pragma unroll
    for (int mi = 0; mi < 4; ++mi)
#pragma unroll
      for (int ni = 0; ni < 2; ++ni) {
        v4s p4;
#pragma unroll
        for (int r = 0; r < 4; ++r) p4[r] = bf16_bits(s[mi][ni][r]);
        const int base = (ni * 2 + (mi >> 1)) * 512 +
                         ((mi & 1) * 2 + (quad >> 1)) * 128 + m16 * 8 + (quad & 1) * 4;
        *(v4s*)&Pw[base] = p4;
      }
    asm volatile("" ::: "memory");  // same-wave: P writes before P frag reads
    __builtin_amdgcn_s_setprio(1);
#pragma unroll
    for (int kpl = 0; kpl < 2; ++kpl) {
      v8s pf0 = *(const v8s*)&Pw[(0 * 2 + kpl) * 512 + lane * 8];
      v8s pf1 = *(const v8s*)&Pw[(1 * 2 + kpl) * 512 + lane * 8];
#pragma unroll
      for (int mi2 = 0; mi2 < 8; ++mi2) {
        v8s vf = *(const v8s*)&Vs[(mi2 * 4 + kpl) * 512 + lane * 8];
        acc[mi2][0] = MFMA_16x16x32(vf, pf0, acc[mi2][0]);
        acc[mi2][1] = MFMA_16x16x32(vf, pf1, acc[mi2][1]);
      }
    }
    __builtin_amdgcn_s_setprio(0);
    asm volatile("" ::: "memory");  // half-A reads before half-B overwrites
    // ---- half B: pack P^T (mi 4-7 -> kp 2,3) and PV over kp 2,3 ----
#pragma unroll
    for (int mi = 4; mi < 8; ++mi)
#pragma unroll
      for (int ni = 0; ni < 2; ++ni) {
        const int mloc = mi - 4;
        v4s p4;
#pragma unroll
        for (int r = 0; r < 4; ++r) p4[r] = bf16_bits(s[mi][ni][r]);
        const int base = (ni * 2 + (mloc >> 1)) * 512 +
                         ((mloc & 1) * 2 + (quad >> 1)) * 128 + m16 * 8 + (quad & 1) * 4;
        *(v4s*)&Pw[base] = p4;
      }
    asm volatile("" ::: "memory");
    __builtin_amdgcn_s_setprio(1);
#pragma unroll
    for (int kpl = 0; kpl < 2; ++kpl) {
      v8s pf0 = *(const v8s*)&Pw[(0 * 2 + kpl) * 512 + lane * 8];
      v8s pf1 = *(const v8s*)&Pw[(1 * 2 + kpl) * 512 + lane * 8];
#pragma unroll
      for (int mi2 = 0; mi2 < 8; ++mi2) {
        v8s vf = *(const v8s*)&Vs[(mi2 * 4 + 2 + kpl) * 512 + lane * 8];
        acc[mi2][0] = MFMA_16x16x32(vf, pf0, acc[mi2][0]);
        acc[mi2][1] = MFMA_16x16x32(vf, pf1, acc[mi2][1]);
      }
    }
    __builtin_amdgcn_s_setprio(0);
    // ---- all waves done with Vs -> overwrite with V(kt+1) ----
    asm volatile("" ::: "memory");
    __builtin_amdgcn_s_barrier();
    if (kt < qt) {
      const bf16* vg2 = vg + (size_t)(kt + 1) * 128;
#pragma unroll
      for (int mi = 0; mi < 8; ++mi)
        async_lds16(vg2 + (size_t)mi * 16 * 2048, &Vs[(mi * 4 + w) * 512]);
    }
  }
  // ---- epilogue: O[q][h*128+d], 4 consecutive d per lane -> 8B stores ----
#pragma unroll
  for (int ni = 0; ni < 2; ++ni) {
    const float rl = 1.0f / l_run[ni];
    const size_t qrow = qt * 128 + w * 32 + ni * 16 + m16;
#pragma unroll
    for (int mi2 = 0; mi2 < 8; ++mi2) {
      v4s o4;
#pragma unroll
      for (int r = 0; r < 4; ++r) o4[r] = bf16_bits(acc[mi2][ni][r] * rl);
      *(v4s*)(O + qrow * 4096 + h * 128 + mi2 * 16 + quad * 4) = o4;
    }
  }
}

// ---------------------------------------------------------------------------
extern "C" void kernel_launch(void* const* d_in, const int* in_sizes, int n_in,
                              void* d_out, int out_size, void* d_ws, size_t ws_size,
                              hipStream_t stream) {
  const float* stm = (const float*)d_in[0];  // [2048][4096] fp32
  const float* w_q = (const float*)d_in[1];  // [4096][4096] fp32
  const float* w_k = (const float*)d_in[2];  // [1024][4096] fp32
  const float* w_v = (const float*)d_in[3];  // [1024][4096] fp32
  const float* w_o = (const float*)d_in[4];  // [4096][4096] fp32
  float* out = (float*)d_out;                // [2048][4096] fp32

  const size_t M_STM = (size_t)2048 * 4096;  //  8M
  const size_t M_WQ  = (size_t)4096 * 4096;  // 16M
  const size_t M_WK  = (size_t)1024 * 4096;  //  4M

  bf16* ws      = (bf16*)d_ws;
  // [0, 24M): wqkv (wq 16M | wk 4M | wv 4M) — LIVE until QKV gemm completes.
  // After QKV gemm: wo overlays [0,16M), vT overlays [16M,18M),
  //                 ropeT overlays [18M,18.5M) (dead wk/wv tail).
  bf16* wqkv_bf = ws;
  bf16* wo_bf   = ws;
  bf16* vT      = ws + M_WQ;
  float2* ropeT = (float2*)(ws + 18 * 1024 * 1024);
  // [24M, 32M): stm_bf; after QKV gemm: o_buf
  bf16* stm_bf  = ws + 24 * 1024 * 1024;
  bf16* o_buf   = stm_bf;
  // [32M, ~44.6M): qkv_buf [2048][6144]
  bf16* qkv_buf = ws + 32 * 1024 * 1024;

  cvt_f32_bf16<<<(int)(M_STM / 1024), 256, 0, stream>>>(stm, stm_bf, (int)(M_STM / 4));
  cvt_f32_bf16<<<(int)(M_WQ / 1024), 256, 0, stream>>>(w_q, wqkv_bf, (int)(M_WQ / 4));
  cvt_f32_bf16<<<(int)(M_WK / 1024), 256, 0, stream>>>(w_k, wqkv_bf + M_WQ, (int)(M_WK / 4));
  cvt_f32_bf16<<<(int)(M_WK / 1024), 256, 0, stream>>>(w_v, wqkv_bf + M_WQ + M_WK, (int)(M_WK / 4));

  // fused QKV projection: [2048,4096] x [6144,4096]^T -> [2048,6144]
  gemm_bt11<false><<<dim3(24, 8), 512, 0, stream>>>(stm_bf, wqkv_bf, qkv_buf, 2048, 6144, 4096);

  // wqkv dead NOW; stage w_o into its region and build the rope table in the
  // dead wk/wv tail (launching rope_tab before the QKV gemm clobbers w_k!).
  cvt_f32_bf16<<<(int)(M_WQ / 1024), 256, 0, stream>>>(w_o, wo_bf, (int)(M_WQ / 4));
  rope_tab<<<2048, 64, 0, stream>>>(ropeT);

  rope_kernel<<<dim3(2048, 40), 128, 0, stream>>>(qkv_buf, ropeT);
  vtrans_kernel<<<dim3(64, 32), dim3(32, 8), 0, stream>>>(qkv_buf, vT);
  attn_fused4<<<dim3(16, 32), 256, 0, stream>>>(qkv_buf, vT, o_buf);

  // output projection: [2048,4096] x [4096,4096]^T -> fp32 out
  gemm_bt11<true><<<dim3(16, 8), 512, 0, stream>>>(o_buf, wo_bf, out, 2048, 4096, 4096);
}